// Round 5
// baseline (204.509 us; speedup 1.0000x reference)
//
#include <hip/hip_runtime.h>

// Problem constants
#define B_  2
#define S_  1024
#define FIN 768
#define E_  768
#define H_  12
#define DH  64   // = FH = 64

typedef unsigned int uint;

__device__ __forceinline__ float bcast_lane(float v, int l) {
    return __uint_as_float((uint)__builtin_amdgcn_readlane((int)__float_as_uint(v), l));
}

__device__ __forceinline__ void wsum64x2(float& a, float& b) {
#pragma unroll
    for (int m = 1; m < 64; m <<= 1) {
        a += __shfl_xor(a, m, 64);
        b += __shfl_xor(b, m, 64);
    }
}

// ---------------------------------------------------------------------------
// K1: normalize nnmf_w rows once: Wn[f][d] = W[f][d]/rowsum, WnT[d][f] = Wn[f][d]
// ---------------------------------------------------------------------------
__global__ __launch_bounds__(256) void k_wprep(const float* __restrict__ nw,
                                               float* __restrict__ Wn,
                                               float* __restrict__ WnT) {
    const int tid = threadIdx.x;
    const int f = tid >> 2, q = tid & 3;
    float v[16];
    float s = 0.f;
#pragma unroll
    for (int i = 0; i < 16; ++i) { v[i] = nw[f * 64 + q * 16 + i]; s += v[i]; }
    s += __shfl_xor(s, 1, 64);
    s += __shfl_xor(s, 2, 64);
    const float inv = 1.f / fmaxf(s, 1e-20f);
#pragma unroll
    for (int i = 0; i < 16; ++i) {
        float w = v[i] * inv;
        Wn[f * 64 + q * 16 + i] = w;
        WnT[(q * 16 + i) * 64 + f] = w;
    }
}

// ---------------------------------------------------------------------------
// K2: FUSED embed + nnmf. Block = 64 tokens x 1 head.
// Phase 1 (GEMM): xe = clip(x @ embed_w^T + b, 1e-6), 4x4 thread tile,
//   2 ds_read_b128 per 16 FMA (LDS-issue economy).
// Phase 2 (epilogue): l1norm per token -> Inp stashed in LDS (reuses As).
// Phase 3 (nnmf): 4 waves x 16 tokens (processed in pairs for ILP),
//   W in 128 VGPRs; writes h, hri, atomicAdds it0 alpha partial into mp0.
// ---------------------------------------------------------------------------
__global__ __launch_bounds__(256) void k_embed_nnmf(const float* __restrict__ xs,
                                                    const float* __restrict__ ew,
                                                    const float* __restrict__ eb,
                                                    const float* __restrict__ Wn,
                                                    const float* __restrict__ WnT,
                                                    float* __restrict__ hout,
                                                    float* __restrict__ hriout,
                                                    float* __restrict__ mp0) {
    __shared__ float As[64 * 68];   // [k][tok] during GEMM; [tok][d] Inp after
    __shared__ float Bs[64 * 68];   // [k][out]
    const int tid = threadIdx.x;
    const int head = blockIdx.y;
    const int tok0 = blockIdx.x * 64;      // 0..1984
    const int b = tok0 >> 10, s0 = tok0 & 1023;
    const int og = tid & 15;               // out quad (4 outs)
    const int tg = tid >> 4;               // token quad (4 tokens)
    const int lane = tid & 63;

    float acc[4][4];
#pragma unroll
    for (int i = 0; i < 4; ++i)
#pragma unroll
        for (int j = 0; j < 4; ++j) acc[i][j] = 0.f;

    // staging: thread loads 16 consecutive k of one row
    const int row = tid >> 2;              // 0..63
    const int kq = (tid & 3) * 16;
    const float* xrow = xs + (size_t)(tok0 + row) * FIN + kq;
    const float* wrow_g = ew + (size_t)(head * 64 + row) * FIN + kq;

    float4 pa[4], pb[4];
#pragma unroll
    for (int c = 0; c < 4; ++c) {
        pa[c] = *(const float4*)(xrow + c * 4);
        pb[c] = *(const float4*)(wrow_g + c * 4);
    }

    for (int kb = 0; kb < FIN; kb += 64) {
        __syncthreads();   // previous panel's compute done
#pragma unroll
        for (int c = 0; c < 4; ++c) {
            int k = kq + c * 4;
            As[(k + 0) * 68 + row] = pa[c].x; As[(k + 1) * 68 + row] = pa[c].y;
            As[(k + 2) * 68 + row] = pa[c].z; As[(k + 3) * 68 + row] = pa[c].w;
            Bs[(k + 0) * 68 + row] = pb[c].x; Bs[(k + 1) * 68 + row] = pb[c].y;
            Bs[(k + 2) * 68 + row] = pb[c].z; Bs[(k + 3) * 68 + row] = pb[c].w;
        }
        __syncthreads();
        if (kb + 64 < FIN) {   // prefetch next panel during compute
#pragma unroll
            for (int c = 0; c < 4; ++c) {
                pa[c] = *(const float4*)(xrow + kb + 64 + c * 4);
                pb[c] = *(const float4*)(wrow_g + kb + 64 + c * 4);
            }
        }
#pragma unroll 8
        for (int k = 0; k < 64; ++k) {
            float4 a4 = *(const float4*)&As[k * 68 + tg * 4];
            float4 b4 = *(const float4*)&Bs[k * 68 + og * 4];
            float a[4] = {a4.x, a4.y, a4.z, a4.w};
            float bb[4] = {b4.x, b4.y, b4.z, b4.w};
#pragma unroll
            for (int i = 0; i < 4; ++i)
#pragma unroll
                for (int j = 0; j < 4; ++j) acc[i][j] = fmaf(a[i], bb[j], acc[i][j]);
        }
    }

    // load W fragments (latency overlaps epilogue + barriers)
    float wcol[64], wrw[64];
#pragma unroll
    for (int f = 0; f < 64; ++f) wcol[f] = Wn[f * 64 + lane];   // W[f][lane]
#pragma unroll
    for (int d = 0; d < 64; ++d) wrw[d] = WnT[d * 64 + lane];   // W[lane][d]

    // epilogue: bias, clamp, per-token l1norm over the 64 outs; stash in LDS
    float4 bias4 = *(const float4*)(eb + head * 64 + og * 4);
    float bias[4] = {bias4.x, bias4.y, bias4.z, bias4.w};
    float vals[4][4];
    float invs[4];
#pragma unroll
    for (int i = 0; i < 4; ++i) {
        float p = 0.f;
#pragma unroll
        for (int j = 0; j < 4; ++j) {
            float xe = fmaxf(acc[i][j] + bias[j], 1e-6f);
            vals[i][j] = xe;
            p += xe;
        }
        p += __shfl_xor(p, 1, 64);
        p += __shfl_xor(p, 2, 64);
        p += __shfl_xor(p, 4, 64);
        p += __shfl_xor(p, 8, 64);
        invs[i] = 1.f / fmaxf(p, 1e-20f);
    }
    __syncthreads();   // all waves done reading As/Bs (final panel)
#pragma unroll
    for (int i = 0; i < 4; ++i) {
        int t = tg * 4 + i;
        float4 o;
        o.x = vals[i][0] * invs[i]; o.y = vals[i][1] * invs[i];
        o.z = vals[i][2] * invs[i]; o.w = vals[i][3] * invs[i];
        *(float4*)&As[t * 68 + og * 4] = o;   // Inp[t][d]
    }
    __syncthreads();

    // ---- nnmf phase: wave wv handles tokens wv*16 .. +15, in pairs ----
    const int wv = tid >> 6;
    const size_t thBase = ((size_t)(b * 12 + head) * 1024 + s0) * 64;
    float hsum = 0.f;
    for (int pp = 0; pp < 8; ++pp) {
        const int t0 = wv * 16 + pp * 2;
        float iv[2] = {As[t0 * 68 + lane], As[(t0 + 1) * 68 + lane]};
        float hv[2] = {1.f / 64.f, 1.f / 64.f};
        float rec[2] = {0.f, 0.f};
        for (int it = 0; it < 3; ++it) {
            float ta[2] = {0.f, 0.f}, tb[2] = {0.f, 0.f};
#pragma unroll
            for (int f = 0; f < 64; f += 2) {
#pragma unroll
                for (int p = 0; p < 2; ++p) {
                    ta[p] = fmaf(bcast_lane(hv[p], f    ), wcol[f    ], ta[p]);
                    tb[p] = fmaf(bcast_lane(hv[p], f + 1), wcol[f + 1], tb[p]);
                }
            }
            float t[2], w[2];
            t[0] = fmaxf(ta[0] + tb[0], 1e-6f);
            t[1] = fmaxf(ta[1] + tb[1], 1e-6f);
            w[0] = t[0]; w[1] = t[1];
            wsum64x2(w[0], w[1]);
            rec[0] = t[0] / fmaxf(w[0], 1e-20f);
            rec[1] = t[1] / fmaxf(w[1], 1e-20f);
            float q[2] = {iv[0] / rec[0], iv[1] / rec[1]};
            float ua[2] = {0.f, 0.f}, ub[2] = {0.f, 0.f};
#pragma unroll
            for (int d = 0; d < 64; d += 2) {
#pragma unroll
                for (int p = 0; p < 2; ++p) {
                    ua[p] = fmaf(bcast_lane(q[p], d    ), wrw[d    ], ua[p]);
                    ub[p] = fmaf(bcast_lane(q[p], d + 1), wrw[d + 1], ub[p]);
                }
            }
            float hn[2];
            hn[0] = fmaxf(hv[0] * (ua[0] + ub[0]), 1e-6f);
            hn[1] = fmaxf(hv[1] * (ua[1] + ub[1]), 1e-6f);
            float wn[2] = {hn[0], hn[1]};
            wsum64x2(wn[0], wn[1]);
            hv[0] = hn[0] / fmaxf(wn[0], 1e-20f);
            hv[1] = hn[1] / fmaxf(wn[1], 1e-20f);
        }
        float fs[2] = {hv[0], hv[1]};
        wsum64x2(fs[0], fs[1]);
        hv[0] = hv[0] / fmaxf(fs[0], 1e-20f);
        hv[1] = hv[1] / fmaxf(fs[1], 1e-20f);
        hout[thBase + (size_t)t0 * 64 + lane] = hv[0];
        hout[thBase + (size_t)(t0 + 1) * 64 + lane] = hv[1];
        hriout[thBase + (size_t)t0 * 64 + lane] = rec[0] * iv[0];
        hriout[thBase + (size_t)(t0 + 1) * 64 + lane] = rec[1] * iv[1];
        hsum += hv[0] + hv[1];
    }
    // it=0 alpha partial for this block's (single) 64-token chunk
    atomicAdd(&mp0[((size_t)(b * 12 + head) * 16 + (s0 >> 6)) * 64 + lane], hsum);
}

// ---------------------------------------------------------------------------
// K3: one alpha iteration per launch, 384 blocks = (bh) x (64-o chunk).
//   m = sum of 16 chunk partials; v = 1/(mW+eps); c[o] *= hri[o]·v; emit
//   partial m (it<3) or atomicAdd into M (it==3).
// ---------------------------------------------------------------------------
__global__ __launch_bounds__(256) void k_alpha_step(const float* __restrict__ hin,
                                                    const float* __restrict__ hri,
                                                    const float* __restrict__ Wn,
                                                    const float* __restrict__ mp_in,
                                                    float* __restrict__ mp_out,
                                                    float* __restrict__ c,
                                                    float* __restrict__ M,
                                                    int it) {
    __shared__ float mred[4][64];
    __shared__ float mv[64];
    __shared__ float vv[64];
    __shared__ float cl[64];
    const int tid = threadIdx.x;
    const int bh = blockIdx.x >> 4;
    const int chunk = blockIdx.x & 15;
    const size_t rowbase = (size_t)bh * 1024 + chunk * 64;

    {   // m[f] = sum over 16 chunks of mp_in[bh][ch][f]
        int f = tid & 63, p = tid >> 6;
        float s = 0.f;
#pragma unroll
        for (int pp = 0; pp < 4; ++pp)
            s += mp_in[((size_t)bh * 16 + p * 4 + pp) * 64 + f];
        mred[p][f] = s;
    }
    __syncthreads();
    if (tid < 64)
        mv[tid] = (mred[0][tid] + mred[1][tid]) + (mred[2][tid] + mred[3][tid]);
    __syncthreads();
    {   // v[d] = 1/(sum_f m[f]*W[f][d] + eps)
        int d = tid & 63, qq = tid >> 6;
        float r = 0.f;
#pragma unroll
        for (int ff = 0; ff < 16; ++ff)
            r = fmaf(mv[qq * 16 + ff], Wn[(size_t)(qq * 16 + ff) * 64 + d], r);
        mred[qq][d] = r;
    }
    __syncthreads();
    if (tid < 64)
        vv[tid] = 1.f / (((mred[0][tid] + mred[1][tid]) + (mred[2][tid] + mred[3][tid])) + 1e-20f);
    __syncthreads();
    {   // c-update: c[o] *= dot(hri[o,:], v)
        int o = tid >> 2, dq = tid & 3;
        const float* rp = hri + (rowbase + o) * 64 + dq * 16;
        float dot = 0.f;
#pragma unroll
        for (int t4 = 0; t4 < 16; t4 += 4) {
            float4 r4 = *(const float4*)(rp + t4);
            dot = fmaf(r4.x, vv[dq * 16 + t4 + 0], dot);
            dot = fmaf(r4.y, vv[dq * 16 + t4 + 1], dot);
            dot = fmaf(r4.z, vv[dq * 16 + t4 + 2], dot);
            dot = fmaf(r4.w, vv[dq * 16 + t4 + 3], dot);
        }
        dot += __shfl_xor(dot, 1, 64);
        dot += __shfl_xor(dot, 2, 64);
        float cn = dot;
        if (it >= 2) cn *= c[rowbase + o];
        if (dq == 0) { c[rowbase + o] = cn; cl[o] = cn; }
    }
    __syncthreads();
    {   // partial m for this chunk: m_c[f] = sum_{o in chunk} h[o,f] * cl[o]
        const int f4 = (tid & 15) * 4, ogr = tid >> 4;
        float4 a = make_float4(0.f, 0.f, 0.f, 0.f);
#pragma unroll
        for (int oi = 0; oi < 4; ++oi) {
            int o = ogr * 4 + oi;
            float4 h4 = *(const float4*)(hin + (rowbase + o) * 64 + f4);
            float cv = cl[o];
            a.x = fmaf(h4.x, cv, a.x); a.y = fmaf(h4.y, cv, a.y);
            a.z = fmaf(h4.z, cv, a.z); a.w = fmaf(h4.w, cv, a.w);
        }
        a.x += __shfl_xor(a.x, 16, 64); a.y += __shfl_xor(a.y, 16, 64);
        a.z += __shfl_xor(a.z, 16, 64); a.w += __shfl_xor(a.w, 16, 64);
        a.x += __shfl_xor(a.x, 32, 64); a.y += __shfl_xor(a.y, 32, 64);
        a.z += __shfl_xor(a.z, 32, 64); a.w += __shfl_xor(a.w, 32, 64);
        const int w = tid >> 6;
        if ((tid & 63) < 16) *(float4*)&mred[w][(tid & 15) * 4] = a;
    }
    __syncthreads();
    if (tid < 64) {
        float s = (mred[0][tid] + mred[1][tid]) + (mred[2][tid] + mred[3][tid]);
        if (it == 3) atomicAdd(&M[(size_t)bh * 64 + tid], s);
        else mp_out[((size_t)bh * 16 + chunk) * 64 + tid] = s;
    }
}

// ---------------------------------------------------------------------------
// K4: out-projection + broadcast, 384 blocks = (b) x (12 out-seg) x (16 rowgrp).
// Each block redundantly computes its 64-out y-segment, stores 64 rows.
// ---------------------------------------------------------------------------
__global__ __launch_bounds__(256) void k_projbcast(const float* __restrict__ M,
                                                   const float* __restrict__ ow,
                                                   const float* __restrict__ ob,
                                                   float* __restrict__ out) {
    __shared__ float Ml[768];
    __shared__ float ps[4][64];
    __shared__ float yseg[64];
    const int tid = threadIdx.x;
    const int b = blockIdx.x / 192;
    const int rem = blockIdx.x - b * 192;
    const int jt = rem >> 4, rg = rem & 15;
    for (int i = tid; i < 768; i += 256) Ml[i] = M[b * 768 + i];
    __syncthreads();
    const int jj = tid & 63, part = tid >> 6;
    const int j = jt * 64 + jj;
    const float* row = ow + (size_t)j * 768 + part * 192;
    float acc = 0.f;
    for (int t = 0; t < 192; t += 4) {
        float4 w4 = *(const float4*)(row + t);
        acc = fmaf(w4.x, Ml[part * 192 + t + 0], acc);
        acc = fmaf(w4.y, Ml[part * 192 + t + 1], acc);
        acc = fmaf(w4.z, Ml[part * 192 + t + 2], acc);
        acc = fmaf(w4.w, Ml[part * 192 + t + 3], acc);
    }
    ps[part][jj] = acc;
    __syncthreads();
    if (tid < 64)
        yseg[tid] = ps[0][tid] + ps[1][tid] + ps[2][tid] + ps[3][tid] + ob[jt * 64 + tid];
    __syncthreads();
    // store 64 rows (rg*64 .. +63) of this (b, jt) segment
    const int r0 = tid >> 2, c4 = (tid & 3) * 16;
    float4 v4[4];
#pragma unroll
    for (int q = 0; q < 4; ++q) v4[q] = *(const float4*)&yseg[c4 + q * 4];
    float* dst = out + ((size_t)(b * 1024 + rg * 64 + r0)) * 768 + jt * 64 + c4;
#pragma unroll
    for (int q = 0; q < 4; ++q) *(float4*)(dst + q * 4) = v4[q];
}

extern "C" void kernel_launch(void* const* d_in, const int* in_sizes, int n_in,
                              void* d_out, int out_size, void* d_ws, size_t ws_size,
                              hipStream_t stream) {
    const float* xs = (const float*)d_in[0];  // [2,1024,768]
    const float* ew = (const float*)d_in[1];  // [768,768]
    const float* eb = (const float*)d_in[2];  // [768]
    const float* nw = (const float*)d_in[3];  // [64,64]
    const float* ow = (const float*)d_in[4];  // [768,768]
    const float* ob = (const float*)d_in[5];  // [768]
    float* out = (float*)d_out;               // [2,1024,768]

    float* ws  = (float*)d_ws;
    float* h   = ws;                 // 1572864
    float* hri = ws + 1572864;       // 1572864
    float* Wn  = ws + 3145728;       // 4096
    float* WnT = ws + 3149824;       // 4096
    float* mp0 = ws + 3153920;       // 24576  (atomic target, zeroed)
    float* M   = ws + 3178496;       // 1536   (atomic target, zeroed; contiguous w/ mp0)
    float* mp1 = ws + 3180032;       // 24576
    float* mp2 = ws + 3204608;       // 24576
    float* c   = ws + 3229184;       // 24576

    hipMemsetAsync(mp0, 0, (24576 + 1536) * sizeof(float), stream);
    k_wprep<<<1, 256, 0, stream>>>(nw, Wn, WnT);
    k_embed_nnmf<<<dim3(32, 12), 256, 0, stream>>>(xs, ew, eb, Wn, WnT, h, hri, mp0);
    k_alpha_step<<<384, 256, 0, stream>>>(h, hri, Wn, mp0, mp1, c, M, 1);
    k_alpha_step<<<384, 256, 0, stream>>>(h, hri, Wn, mp1, mp2, c, M, 2);
    k_alpha_step<<<384, 256, 0, stream>>>(h, hri, Wn, mp2, mp1, c, M, 3);
    k_projbcast<<<384, 256, 0, stream>>>(M, ow, ob, out);
}